// Round 2
// baseline (393.013 us; speedup 1.0000x reference)
//
#include <hip/hip_runtime.h>

#define NF      100
#define BLOCK   64                  // ONE wave per block: zero cross-wave coupling
#define TILE    64                  // rows per tile
#define F4T     (TILE * 25)         // 1600 float4 = exactly 25 per lane (no padding)
#define NLD     25                  // staging issues per wave, exact -> no over-fetch
#define NBUF    3
#define MAXGRID 512                 // 2 blocks/CU; LDS = 3*25.6 + 0.8 = 77.6 KiB

// Wave-uniform staging: every wave issues exactly NLD global_load_lds per tile.
// Per-lane SOURCE clamped in range; DEST = base + lane*16, linear (HW requirement).
__device__ __forceinline__ void stage_tile(const float4* __restrict__ x4,
                                           float4* dst, int f4base, int maxf4,
                                           int tid) {
#pragma unroll
  for (int u = 0; u < NLD; ++u) {
    int g = f4base + u * BLOCK + tid;
    g = g > maxf4 ? maxf4 : g;       // only bites on final partial tile / dummy stages
    __builtin_amdgcn_global_load_lds(
        (const __attribute__((address_space(1))) void*)(x4 + g),
        (__attribute__((address_space(3))) void*)(dst + u * BLOCK + tid),
        16, 0, 0);
  }
}

// s_waitcnt imm: vmcnt[3:0]@[3:0], expcnt@[6:4], lgkmcnt@[11:8], vmcnt[5:4]@[15:14]
// 0x4F7A = vmcnt(26), expcnt(7)=no-wait, lgkmcnt(15)=no-wait.
// Steady FIFO at loop top (oldest first): [S_k(25), store(1), S_{k+1}(25), store(1)]
// = 52 outstanding -> draining to 26 retires exactly S_k + the old store; S_{k+1}
// stays in flight. 52 <= 63 (vmcnt width). Iterations 0/1 enter with 0/26
// outstanding (pre-loop __syncthreads drains S_0,S_1) so the wait is a no-op there.
// NO scratch ops exist in this kernel (VGPR ~150 < 256), so vmcnt counts only
// our stages + the one store: the arithmetic is exact.
#define WAITCNT_VM26 0x4F7A

__global__ __launch_bounds__(BLOCK, 1) void fused_kernel(
    const float4* __restrict__ x4,
    const float* __restrict__ A_real, const float* __restrict__ A_imag,
    const float* __restrict__ psi_real, const float* __restrict__ psi_imag,
    float2* __restrict__ out, int batch, int ntiles) {
  __shared__ float4 xs[NBUF][F4T];            // 76.8 KiB, linear (global_load_lds dest)
  __shared__ __align__(16) float ms2[2][NF];  // M_re[k][a], class-major for float4 reads

  const int tid = threadIdx.x;               // == lane (one wave per block)
  const int maxf4 = batch * 25 - 1;
  const int stride = gridDim.x;

  float4* b0 = &xs[0][0];
  float4* b1 = &xs[1][0];
  float4* b2 = &xs[2][0];

  // Start the x stream IMMEDIATELY so HBM is busy while the A-phase runs.
  int t = blockIdx.x;
  stage_tile(x4, b0, t * F4T, maxf4, tid);             // tile t
  stage_tile(x4, b1, (t + stride) * F4T, maxf4, tid);  // tile t+stride

  // ---- Phase 1 (per-block, redundant, L2-hot): lane a computes M[:,a];
  // lanes 0..35 also cover feature a+64.
  {
    float pr[10], pi[10];
#pragma unroll
    for (int i = 0; i < 10; ++i) { pr[i] = psi_real[i]; pi[i] = psi_imag[i]; }
    const bool two = tid < (NF - BLOCK);     // 36 lanes take a second feature
    float m0 = 0.f, m1 = 0.f, n0 = 0.f, n1 = 0.f;
#pragma unroll
    for (int i = 0; i < 10; ++i) {
#pragma unroll
      for (int j = 0; j < 10; ++j) {
        float pre = pr[i] * pr[j] + pi[i] * pi[j];
        float pim = pr[i] * pi[j] - pi[i] * pr[j];
        int off = (i * 10 + j) * NF + tid;          // k=0, feature tid
        m0 = fmaf(pre, A_real[off], m0);
        m0 = fmaf(-pim, A_imag[off], m0);
        m1 = fmaf(pre, A_real[off + 10000], m1);    // k=1
        m1 = fmaf(-pim, A_imag[off + 10000], m1);
        if (two) {
          n0 = fmaf(pre, A_real[off + BLOCK], n0);  // feature tid+64
          n0 = fmaf(-pim, A_imag[off + BLOCK], n0);
          n1 = fmaf(pre, A_real[off + BLOCK + 10000], n1);
          n1 = fmaf(-pim, A_imag[off + BLOCK + 10000], n1);
        }
      }
    }
    ms2[0][tid] = m0;
    ms2[1][tid] = m1;
    if (two) { ms2[0][tid + BLOCK] = n0; ms2[1][tid + BLOCK] = n1; }
  }
  // One-time full drain (vmcnt(0)+lgkmcnt(0) implied): S_0, S_1 land here (issued
  // at cycle ~0, latency hidden under the A-phase); ms2 writes fenced.
  __syncthreads();

  // ---- Class-split M into registers: lane holds M[k][0..99] = 25 float4 =
  // 100 VGPRs. Total pressure ~150 -> NO spill (round-1 lesson: mreg[50] = 200
  // float4-VGPRs blew the 256 architected cap and spilled to scratch).
  const int k  = tid & 1;    // class this lane accumulates
  const int r2 = tid >> 1;   // row pair index: lane owns rows r2 and r2+32
  const float4* mk = (const float4*)ms2[k];
  float4 mreg[25];
#pragma unroll
  for (int j = 0; j < 25; ++j) mreg[j] = mk[j];

  // ---- Phase 2: persistent, triple-buffered, single-wave stream.
  for (; t < ntiles; t += stride) {
    __builtin_amdgcn_s_waitcnt(WAITCNT_VM26);  // retire exactly this tile's stage
    __builtin_amdgcn_s_barrier();              // 1-wave: free; compiler LDS fence

    stage_tile(x4, b2, (t + 2 * stride) * F4T, maxf4, tid);  // reuse oldest buf

    const float4* xrowA = b0 + r2 * 25;          // row r2 (pair-broadcast reads)
    const float4* xrowB = b0 + (r2 + 32) * 25;   // row r2+32
    float accA = 0.f, accB = 0.f;                // class k for rows r2 / r2+32
#pragma unroll
    for (int j = 0; j < 25; ++j) {
      float4 xa = xrowA[j];
      float4 xb = xrowB[j];
      float4 m  = mreg[j];
      accA = fmaf(xa.x, m.x, accA); accB = fmaf(xb.x, m.x, accB);
      accA = fmaf(xa.y, m.y, accA); accB = fmaf(xb.y, m.y, accB);
      accA = fmaf(xa.z, m.z, accA); accB = fmaf(xb.z, m.z, accB);
      accA = fmaf(xa.w, m.w, accA); accB = fmaf(xb.w, m.w, accB);
    }
    // Pair up (a0,a1): partner lane (tid^1) has the other class for the same rows.
    const float oA = __shfl_xor(accA, 1);  // even lane: a1(r2)   ; odd: a0(r2)
    const float oB = __shfl_xor(accB, 1);  // even lane: a1(r2+32); odd: a0(r2+32)
    const int t0 = t * TILE;
    const int row = k == 0 ? r2 : r2 + 32;
    const float2 val = k == 0 ? make_float2(accA, oA) : make_float2(oB, accB);
    if (row < batch - t0) out[t0 + row] = val;
    // Full tiles: all 64 lanes store. Last tile (32 valid rows): even lanes
    // store, exec!=0, instruction still issues -> vmcnt count stays uniform.

    float4* tmp = b0; b0 = b1; b1 = b2; b2 = tmp;
  }
}

extern "C" void kernel_launch(void* const* d_in, const int* in_sizes, int n_in,
                              void* d_out, int out_size, void* d_ws, size_t ws_size,
                              hipStream_t stream) {
  const float* x  = (const float*)d_in[0];
  const float* Ar = (const float*)d_in[1];
  const float* Ai = (const float*)d_in[2];
  const float* pr = (const float*)d_in[3];
  const float* pi = (const float*)d_in[4];
  const int batch = in_sizes[0] / NF;

  const int ntiles = (batch + TILE - 1) / TILE;
  const int grid = ntiles < MAXGRID ? ntiles : MAXGRID;
  fused_kernel<<<grid, BLOCK, 0, stream>>>(
      (const float4*)x, Ar, Ai, pr, pi, (float2*)d_out, batch, ntiles);
}

// Round 3
// 288.043 us; speedup vs baseline: 1.3644x; 1.3644x over previous
//
#include <hip/hip_runtime.h>

#define NF      100
#define BLOCK   128                 // 2 waves (round-0 proven sync skeleton)
#define TILE    32                  // rows per tile
#define F4T     (TILE * 25)         // 800 float4 = 12.8 KB real data per tile
#define NLD     7                   // ceil(800/128) issues per wave, ALWAYS 7
#define F4PAD   (NLD * BLOCK)       // 896: dest pad (written with dup line, never read)
#define NBUF    3
#define MAXGRID 768                 // 3 blocks/CU; LDS = 3*14.0 + 0.8 = 43.8 KiB

// Wave-uniform staging: every wave issues exactly NLD global_load_lds.
// DEST is linear (HW: wave-uniform base + lane*16). SOURCE for the pad region
// (idx >= F4T) is redirected to the tile's own first line -> it is an L2 hit on
// a line we fetch anyway: ZERO structural over-fetch (round-0 paid 4% here).
__device__ __forceinline__ void stage_tile(const float4* __restrict__ x4,
                                           float4* dst, int f4base, int maxf4,
                                           int tid) {
#pragma unroll
  for (int u = 0; u < NLD; ++u) {
    int idx = u * BLOCK + tid;
    int g = f4base + (idx < F4T ? idx : 0);  // pad -> dup of tile's first line
    g = g > maxf4 ? maxf4 : g;               // dummy epilogue stages clamp in-range
    __builtin_amdgcn_global_load_lds(
        (const __attribute__((address_space(1))) void*)(x4 + g),
        (__attribute__((address_space(3))) void*)(dst + idx),
        16, 0, 0);
  }
}

// s_waitcnt imm: vmcnt[3:0]@[3:0], expcnt@[6:4], lgkmcnt@[11:8], vmcnt[5:4]@[15:14]
// 0x0F78 = vmcnt(8), expcnt(7)=no-wait, lgkmcnt(15)=no-wait.
// Steady FIFO at loop top (oldest first): [S_k(7), st_{k-2}(1), S_{k+1}(7),
// st_{k-1}(1)] = 16 -> draining to 8 retires exactly S_k + the old store; the
// in-flight next stage survives. Iter 0/1 enter with 0/8 outstanding (pre-loop
// __syncthreads drains S_0,S_1) so the wait is a no-op there. Register pressure
// (~120 VGPR, see mreg sizing below) guarantees NO scratch ops pollute vmcnt —
// rounds 1-2 died exactly there (VGPR=256 pegged, 9-28 MB spill traffic).
#define WAITCNT_VM8_NOLGKM 0x0F78

__global__ __launch_bounds__(BLOCK, 1) void fused_kernel(
    const float4* __restrict__ x4,
    const float* __restrict__ A_real, const float* __restrict__ A_imag,
    const float* __restrict__ psi_real, const float* __restrict__ psi_imag,
    float2* __restrict__ out, int batch, int ntiles) {
  __shared__ float4 xs[NBUF][F4PAD];         // 42 KiB, linear (global_load_lds dest)
  __shared__ __align__(16) float2 msl[NF];   // (M_re[0,a], M_re[1,a]) per feature

  const int tid = threadIdx.x;
  const int maxf4 = batch * 25 - 1;
  const int stride = gridDim.x;

  float4* b0 = &xs[0][0];
  float4* b1 = &xs[1][0];
  float4* b2 = &xs[2][0];

  // Start the x stream IMMEDIATELY so HBM is busy while the A-phase runs.
  int t = blockIdx.x;
  stage_tile(x4, b0, t * F4T, maxf4, tid);             // tile t
  stage_tile(x4, b1, (t + stride) * F4T, maxf4, tid);  // tile t+stride

  // ---- Phase 1 (per-block, redundant, L2-hot): M_re[k,a] — round-0 verbatim.
  if (tid < NF) {
    const int a = tid;
    float pr[10], pi[10];
#pragma unroll
    for (int i = 0; i < 10; ++i) { pr[i] = psi_real[i]; pi[i] = psi_imag[i]; }
    float m0 = 0.f, m1 = 0.f;
#pragma unroll
    for (int i = 0; i < 10; ++i) {
#pragma unroll
      for (int j = 0; j < 10; ++j) {
        float pre = pr[i] * pr[j] + pi[i] * pi[j];
        float pim = pr[i] * pi[j] - pi[i] * pr[j];
        int off = (i * 10 + j) * NF + a;          // k=0
        m0 = fmaf(pre, A_real[off], m0);
        m0 = fmaf(-pim, A_imag[off], m0);
        m1 = fmaf(pre, A_real[off + 10000], m1);  // k=1
        m1 = fmaf(-pim, A_imag[off + 10000], m1);
      }
    }
    msl[a] = make_float2(m0, m1);
  }
  // One-time full drain (vmcnt(0)+lgkmcnt(0) implied): S_0, S_1 land here (their
  // latency hid under the A-phase); msl writes fenced for all waves.
  __syncthreads();

  // ---- Quarter-split: 4 lanes per row. Lane (r,q) owns chunks j = q + 4i.
  // mreg = 7 chunks x 2 float4 = 14 float4 = 56 VGPRs; with <=7 x-float4 in
  // flight total pressure ~120 -> no spill possible (the round-1/2 lesson).
  const int q = tid & 3;    // chunk quarter
  const int r = tid >> 2;   // row within tile (0..31)
  const float4* msl4 = (const float4*)msl;   // msl4[2j],[2j+1] = features 4j..4j+3
  float4 mreg[14];
#pragma unroll
  for (int i = 0; i < 7; ++i) {
    int j = q + 4 * i;
    int jc = j < 25 ? j : 24;                // q>0,i=6: clamped load, fma predicated off
    mreg[2 * i]     = msl4[2 * jc];
    mreg[2 * i + 1] = msl4[2 * jc + 1];
  }

  // ---- Phase 2: persistent triple-buffered stream over tiles.
  for (; t < ntiles; t += stride) {
    // Retire exactly this tile's stage (+2-old store); next stage stays in flight.
    __builtin_amdgcn_s_waitcnt(WAITCNT_VM8_NOLGKM);
    __builtin_amdgcn_s_barrier();

    stage_tile(x4, b2, (t + 2 * stride) * F4T, maxf4, tid);  // reuse oldest buf

    const float4* xrow = b0 + r * 25 + q;   // chunks q, q+4, ..., stride 4
    float a0 = 0.f, a1 = 0.f;
#pragma unroll
    for (int i = 0; i < 7; ++i) {
      if (i < 6 || q == 0) {                // q=0 has 7 chunks (j=24), others 6
        float4 xv = xrow[4 * i];
        float4 mA = mreg[2 * i];            // features f,f+1 as (m0,m1,m0,m1)
        float4 mB = mreg[2 * i + 1];        // features f+2,f+3
        a0 = fmaf(xv.x, mA.x, a0); a1 = fmaf(xv.x, mA.y, a1);
        a0 = fmaf(xv.y, mA.z, a0); a1 = fmaf(xv.y, mA.w, a1);
        a0 = fmaf(xv.z, mB.x, a0); a1 = fmaf(xv.z, mB.y, a1);
        a0 = fmaf(xv.w, mB.z, a0); a1 = fmaf(xv.w, mB.w, a1);
      }
    }
    // Reduce across the 4 lanes of the row (q dimension).
    a0 += __shfl_xor(a0, 1); a0 += __shfl_xor(a0, 2);
    a1 += __shfl_xor(a1, 1); a1 += __shfl_xor(a1, 2);
    const int t0 = t * TILE;
    if (q == 0 && r < batch - t0) out[t0 + r] = make_float2(a0, a1);
    // 16 store-lanes per wave (128 B contiguous) -> the store instruction always
    // issues in BOTH waves -> per-wave vmcnt count stays uniform at 7+1.

    float4* tmp = b0; b0 = b1; b1 = b2; b2 = tmp;
  }
}

extern "C" void kernel_launch(void* const* d_in, const int* in_sizes, int n_in,
                              void* d_out, int out_size, void* d_ws, size_t ws_size,
                              hipStream_t stream) {
  const float* x  = (const float*)d_in[0];
  const float* Ar = (const float*)d_in[1];
  const float* Ai = (const float*)d_in[2];
  const float* pr = (const float*)d_in[3];
  const float* pi = (const float*)d_in[4];
  const int batch = in_sizes[0] / NF;

  const int ntiles = (batch + TILE - 1) / TILE;
  const int grid = ntiles < MAXGRID ? ntiles : MAXGRID;
  fused_kernel<<<grid, BLOCK, 0, stream>>>(
      (const float4*)x, Ar, Ai, pr, pi, (float2*)d_out, batch, ntiles);
}